// Round 2
// baseline (317.564 us; speedup 1.0000x reference)
//
#include <hip/hip_runtime.h>
#include <hip/hip_bf16.h>

typedef __attribute__((ext_vector_type(8)))  short s8v;   // 8 bf16
typedef __attribute__((ext_vector_type(4)))  float f4v;   // 16x16 C/D
typedef _Float16 h4 __attribute__((ext_vector_type(4)));  // 4 f16
typedef _Float16 h8 __attribute__((ext_vector_type(8)));  // 8 f16

constexpr int Dd   = 256;
constexpr int NCn  = 128;
constexpr int DDn  = 65536;
constexpr int XP   = 264;             // padded LDS row (bf16 elems)
constexpr int SSP  = 24;              // padded score row (f16 elems, 48B)
constexpr float EPSf = 1.1920929e-07f;

__device__ __forceinline__ float sigm(float x){ return 1.0f/(1.0f + expf(-x)); }
__device__ __forceinline__ float silu_(float x){ return x * sigm(x); }
__device__ __forceinline__ float dsilu_(float x){ float s = sigm(x); return s*(1.0f + x*(1.0f - s)); }

__device__ __forceinline__ unsigned short f2b(float x){
    __hip_bfloat16 b = __float2bfloat16(x);
    unsigned short u; __builtin_memcpy(&u, &b, 2); return u;
}
__device__ __forceinline__ float b2f(unsigned short u){
    __hip_bfloat16 b; __builtin_memcpy(&b, &u, 2); return __bfloat162float(b);
}
__device__ __forceinline__ unsigned short f2hu(float x){
    _Float16 h = (_Float16)x;
    unsigned short u; __builtin_memcpy(&u, &h, 2); return u;
}
__device__ __forceinline__ h8 ldh8(const void* p){
    h8 r; __builtin_memcpy(&r, p, 16); return r;
}

__device__ __forceinline__ float block_sum(float v, float* red){   // 256 thr
    #pragma unroll
    for (int off = 32; off; off >>= 1) v += __shfl_down(v, off, 64);
    if ((threadIdx.x & 63) == 0) red[threadIdx.x >> 6] = v;
    __syncthreads();
    float r = red[0] + red[1] + red[2] + red[3];
    __syncthreads();
    return r;
}
__device__ __forceinline__ float block_sum8(float v, float* red){  // 512 thr
    #pragma unroll
    for (int off = 32; off; off >>= 1) v += __shfl_down(v, off, 64);
    if ((threadIdx.x & 63) == 0) red[threadIdx.x >> 6] = v;
    __syncthreads();
    float r = 0.f;
    #pragma unroll
    for (int i = 0; i < 8; ++i) r += red[i];
    __syncthreads();
    return r;
}

// ---- merged weight prep: z 0..5 tiled transpose fp32->bf16, z 6..8 cast-copy ----
__global__ __launch_bounds__(256) void ktw(const float* __restrict__ Wq,
        const float* __restrict__ Wkv, const float* __restrict__ W0,
        const float* __restrict__ W1, const float* __restrict__ W2,
        const float* __restrict__ W3, unsigned short* __restrict__ WTb,
        unsigned short* __restrict__ WqTb, unsigned short* __restrict__ WkvTb,
        unsigned short* __restrict__ Wb){
    int z = blockIdx.z;
    if (z >= 6){
        const float* S = (z==6)?W1:(z==7)?W2:W3;
        size_t idx = (((size_t)blockIdx.y*8 + blockIdx.x)*256 + threadIdx.x)*2;
        float2 v = *(const float2*)(S + idx);
        ushort2 u; u.x = f2b(v.x); u.y = f2b(v.y);
        *(ushort2*)(Wb + (size_t)(z-6)*DDn + idx) = u;
        return;
    }
    __shared__ float tl[32][33];
    if (z != 5 && blockIdx.y >= 8) return;
    const float* S; unsigned short* T; int C;
    if (z < 4){ S = (z==0)?W0:(z==1)?W1:(z==2)?W2:W3; T = WTb + (size_t)z*DDn; C = 256; }
    else if (z == 4){ S = Wq; T = WqTb; C = 256; }
    else { S = Wkv; T = WkvTb; C = 512; }
    int k0 = blockIdx.x*32, j0 = blockIdx.y*32;
    int tx = threadIdx.x & 31, ty = threadIdx.x >> 5;
    #pragma unroll
    for (int p = 0; p < 4; ++p)
        tl[ty + 8*p][tx] = S[(size_t)(k0 + ty + 8*p)*C + j0 + tx];
    __syncthreads();
    #pragma unroll
    for (int p = 0; p < 4; ++p)
        T[(size_t)(j0 + ty + 8*p)*256 + k0 + tx] = f2b(tl[tx][ty + 8*p]);
}

// ---- per-token norm, scatter sn + shifted rn ----
__global__ __launch_bounds__(256) void knorm(const float* __restrict__ seq,
        const float* __restrict__ wsn, const float* __restrict__ wrn,
        unsigned short* __restrict__ snb, unsigned short* __restrict__ rnb){
    __shared__ float red[4];
    int t = blockIdx.x, d = threadIdx.x;
    int b = t >> 10, tl = t & 1023, g = t >> 4, c = tl & 15;
    float x = seq[(size_t)t*256 + d];
    float ss = block_sum(x*x, red);
    float xr = x * rsqrtf(ss*(1.f/256.f) + EPSf);
    snb[(size_t)g*4096 + c*256 + d] = f2b(xr*wsn[d]);
    if (tl >= 15){
        int tl2 = tl - 15, g2 = b*64 + (tl2 >> 4), c2 = tl2 & 15;
        rnb[(size_t)g2*4096 + c2*256 + d] = f2b(xr*wrn[d]);
    }
    if (tl >= 1009)
        rnb[(size_t)g*4096 + c*256 + d] = 0;
}

// ---- fwd + bwd dgrads + fused gates, one block per group ----
// writes Xb: bf16 [l][g][c][d] (layer inputs) and GT: f16 [l][g][d][c] (scaled grads)
__global__ __launch_bounds__(512, 1) void kfb(const unsigned short* __restrict__ snb,
        const unsigned short* __restrict__ WkvTb, const unsigned short* __restrict__ WTb,
        const unsigned short* __restrict__ Wb,
        const float* __restrict__ wa, const float* __restrict__ wm,
        const float* __restrict__ wdk,
        float* __restrict__ momg, float* __restrict__ decg,
        unsigned short* __restrict__ Xb, unsigned short* __restrict__ GT){
    __shared__ unsigned short xl[4][16][XP];
    __shared__ unsigned short Gs[16][XP];
    __shared__ float red8[8];
    int tid = threadIdx.x, w = tid >> 6, lane = tid & 63;
    int m16 = lane & 15, q16 = lane >> 4;
    int g = blockIdx.x;

    float sc;
    {   // fused gates
        int d2 = tid & 255, hf = tid >> 8;
        float a = 0.f;
        #pragma unroll
        for (int c = 0; c < 8; ++c)
            a += b2f(snb[(size_t)g*4096 + (hf*8 + c)*256 + d2]);
        float cm = a * (1.f/16.f);
        float da = block_sum8(cm*wa[d2],  red8);
        float dm = block_sum8(cm*wm[d2],  red8);
        float dc = block_sum8(cm*wdk[d2], red8);
        sc = -2.f * sigm(da) * (1.f/256.f);
        if (tid == 0){ momg[g] = sigm(dm); decg[g] = sigm(dc); }
    }

    s8v af[8];
    const unsigned short* arow = snb + (size_t)g*4096 + m16*256 + q16*8;
    #pragma unroll
    for (int i = 0; i < 8; ++i) af[i] = *(const s8v*)(arow + i*32);

    f4v vacc[2];
    #pragma unroll
    for (int t = 0; t < 2; ++t){
        int n0 = w*32 + t*16;
        f4v ka = {0.f,0.f,0.f,0.f}, va = {0.f,0.f,0.f,0.f};
        const unsigned short* brK = WkvTb + (size_t)(n0 + m16)*256 + q16*8;
        const unsigned short* brV = WkvTb + (size_t)(256 + n0 + m16)*256 + q16*8;
        #pragma unroll
        for (int i = 0; i < 8; ++i){
            s8v bK = *(const s8v*)(brK + i*32);
            s8v bV = *(const s8v*)(brV + i*32);
            ka = __builtin_amdgcn_mfma_f32_16x16x32_bf16(af[i], bK, ka, 0, 0, 0);
            va = __builtin_amdgcn_mfma_f32_16x16x32_bf16(af[i], bV, va, 0, 0, 0);
        }
        vacc[t] = va;
        #pragma unroll
        for (int r = 0; r < 4; ++r) xl[0][4*q16 + r][n0 + m16] = f2b(ka[r]);
    }

    f4v hreg[3][2];
    for (int l = 0; l < 3; ++l){
        __syncthreads();
        s8v xa[8];
        #pragma unroll
        for (int i = 0; i < 8; ++i)
            xa[i] = *(const s8v*)(&xl[l][m16][q16*8 + i*32]);
        const unsigned short* Wt = WTb + (size_t)l*DDn;
        #pragma unroll
        for (int t = 0; t < 2; ++t){
            int n0 = w*32 + t*16;
            f4v acc = {0.f,0.f,0.f,0.f};
            const unsigned short* br = Wt + (size_t)(n0 + m16)*256 + q16*8;
            #pragma unroll
            for (int i = 0; i < 8; ++i){
                s8v b = *(const s8v*)(br + i*32);
                acc = __builtin_amdgcn_mfma_f32_16x16x32_bf16(xa[i], b, acc, 0, 0, 0);
            }
            hreg[l][t] = acc;
            #pragma unroll
            for (int r = 0; r < 4; ++r)
                xl[l+1][4*q16 + r][n0 + m16] = f2b(silu_(acc[r]));
        }
    }
    __syncthreads();

    {   // dump layer inputs Xb[l][g][c][d] bf16 (direct copy from xl)
        int c = tid >> 5, d8 = (tid & 31)*8;
        #pragma unroll
        for (int l = 0; l < 4; ++l)
            *(s8v*)(Xb + (((size_t)l*128 + g)*16 + c)*256 + d8) =
                *(const s8v*)(&xl[l][c][d8]);
    }

    {   // layer 3 (pred) -> Gs
        s8v xa[8];
        #pragma unroll
        for (int i = 0; i < 8; ++i)
            xa[i] = *(const s8v*)(&xl[3][m16][q16*8 + i*32]);
        const unsigned short* Wt = WTb + (size_t)3*DDn;
        #pragma unroll
        for (int t = 0; t < 2; ++t){
            int n0 = w*32 + t*16;
            f4v acc = {0.f,0.f,0.f,0.f};
            const unsigned short* br = Wt + (size_t)(n0 + m16)*256 + q16*8;
            #pragma unroll
            for (int i = 0; i < 8; ++i){
                s8v b = *(const s8v*)(br + i*32);
                acc = __builtin_amdgcn_mfma_f32_16x16x32_bf16(xa[i], b, acc, 0, 0, 0);
            }
            #pragma unroll
            for (int r = 0; r < 4; ++r)
                Gs[4*q16 + r][n0 + m16] = f2b(sc * (acc[r] - vacc[t][r]));
        }
    }
    __syncthreads();
    {   // write f16 GT[3][g][d][c]
        int d = tid & 255, half = tid >> 8;
        s8v v;
        #pragma unroll
        for (int j = 0; j < 8; ++j)
            v[j] = (short)f2hu(b2f(Gs[half*8 + j][d]));
        *(s8v*)(GT + (((size_t)3*128 + g)*256 + d)*16 + half*8) = v;
    }

    for (int l = 3; l >= 1; --l){
        s8v gfa[8];
        #pragma unroll
        for (int i = 0; i < 8; ++i)
            gfa[i] = *(const s8v*)(&Gs[m16][q16*8 + i*32]);
        const unsigned short* Wr = Wb + (size_t)(l-1)*DDn;
        f4v gn[2];
        #pragma unroll
        for (int t = 0; t < 2; ++t){
            int n0 = w*32 + t*16;
            f4v acc = {0.f,0.f,0.f,0.f};
            const unsigned short* br = Wr + (size_t)(n0 + m16)*256 + q16*8;
            #pragma unroll
            for (int i = 0; i < 8; ++i){
                s8v b = *(const s8v*)(br + i*32);
                acc = __builtin_amdgcn_mfma_f32_16x16x32_bf16(gfa[i], b, acc, 0, 0, 0);
            }
            #pragma unroll
            for (int r = 0; r < 4; ++r)
                gn[t][r] = acc[r] * dsilu_(hreg[l-1][t][r]);
        }
        __syncthreads();
        #pragma unroll
        for (int t = 0; t < 2; ++t){
            int n0 = w*32 + t*16;
            #pragma unroll
            for (int r = 0; r < 4; ++r)
                Gs[4*q16 + r][n0 + m16] = f2b(gn[t][r]);
        }
        __syncthreads();
        {
            int d = tid & 255, half = tid >> 8;
            s8v v;
            #pragma unroll
            for (int j = 0; j < 8; ++j)
                v[j] = (short)f2hu(b2f(Gs[half*8 + j][d]));
            *(s8v*)(GT + (((size_t)(l-1)*128 + g)*256 + d)*16 + half*8) = v;
        }
    }
}

// ---- scalar scan coefficients: coeff(g,n) of S_n in updates_g ----
__global__ __launch_bounds__(64) void kcoef(const float* __restrict__ momg,
        const float* __restrict__ decg, float* __restrict__ coefb){
    int b = blockIdx.x, n = threadIdx.x;
    float M = 0.f, cf = 0.f;
    for (int gg = 0; gg < 64; ++gg){
        float mo = momg[b*64 + gg], de = 1.f - decg[b*64 + gg];
        if (gg == n){ M = 1.f; cf = 1.f; }
        else if (gg > n){ M *= mo; cf = de*cf + M; }
        coefb[((size_t)b*64 + gg)*64 + n] = cf;
    }
}

// ---- retrieval: q-proj + 4 fast-weight layers (flash-linear) + post-norm + shift ----
// one block per group g; 4 waves, wave w owns output cols [w*64, w*64+64)
// layer l: h = x@W_l + sum_n coeff(g,n) * (x @ X_n^T) @ G_n
// scores deduped: per 8-chunk block, wave w computes chunks {nb*8+w, nb*8+4+w},
// stages f16 scores in double-buffered LDS, PV consumes 2 chunks per K=32 f16 MFMA.
__global__ __launch_bounds__(256, 1) void kretr(const unsigned short* __restrict__ rnb,
        const unsigned short* __restrict__ WqTb, const unsigned short* __restrict__ WTb,
        const unsigned short* __restrict__ Xb, const unsigned short* __restrict__ GT,
        const float* __restrict__ coefb, const float* __restrict__ wpost,
        float* __restrict__ out){
    __shared__ unsigned short xc[16][XP];
    __shared__ _Float16 ss[2][8][16][SSP];   // [buf][local chunk][j][i]
    __shared__ float red[4][16];
    __shared__ float rs[16];
    int tid = threadIdx.x, w = tid >> 6, lane = tid & 63;
    int m16 = lane & 15, q16 = lane >> 4;
    int g = blockIdx.x, b = g >> 6, nl = g & 63;
    int wq = w*64;
    int c01 = q16 >> 1, koff = (q16 & 1)*8;   // PV pair decomposition

    {   // q-projection (no silu, no update term)
        s8v a[8];
        const unsigned short* ar = rnb + (size_t)g*4096 + m16*256 + q16*8;
        #pragma unroll
        for (int i = 0; i < 8; ++i) a[i] = *(const s8v*)(ar + i*32);
        #pragma unroll
        for (int t = 0; t < 4; ++t){
            int n0 = wq + t*16;
            f4v acc = {0.f,0.f,0.f,0.f};
            const unsigned short* br = WqTb + (size_t)(n0 + m16)*256 + q16*8;
            #pragma unroll
            for (int i = 0; i < 8; ++i){
                s8v bb = *(const s8v*)(br + i*32);
                acc = __builtin_amdgcn_mfma_f32_16x16x32_bf16(a[i], bb, acc, 0, 0, 0);
            }
            #pragma unroll
            for (int r = 0; r < 4; ++r) xc[4*q16 + r][n0 + m16] = f2b(acc[r]);
        }
    }
    __syncthreads();

    f4v hacc[4];
    const float* cfp = coefb + (size_t)g*64;
    int pb = 0;
    int nb8 = (nl + 8) >> 3;                  // ceil((nl+1)/8)
    for (int l = 0; l < 4; ++l){
        s8v xa[8];
        #pragma unroll
        for (int i = 0; i < 8; ++i)
            xa[i] = *(const s8v*)(&xc[m16][q16*8 + i*32]);
        // dense part: x @ W_l
        const unsigned short* Wt = WTb + (size_t)l*DDn;
        #pragma unroll
        for (int t = 0; t < 4; ++t){
            int n0 = wq + t*16;
            f4v acc = {0.f,0.f,0.f,0.f};
            const unsigned short* br = Wt + (size_t)(n0 + m16)*256 + q16*8;
            #pragma unroll
            for (int i = 0; i < 8; ++i){
                s8v bb = *(const s8v*)(br + i*32);
                acc = __builtin_amdgcn_mfma_f32_16x16x32_bf16(xa[i], bb, acc, 0, 0, 0);
            }
            hacc[t] = acc;
        }
        // flash-linear part over chunks n<=nl, 8 chunks per staged block
        const unsigned short* Xl = Xb + ((size_t)l*128 + b*64)*4096;
        const unsigned short* Gl = GT + ((size_t)l*128 + b*64)*4096;
        for (int nb = 0; nb < nb8; ++nb){
            // scores for this wave's two chunks -> ss[pb]
            #pragma unroll
            for (int h = 0; h < 2; ++h){
                int lc  = h*4 + w;
                int cid = nb*8 + lc;
                float cf = (cid <= nl) ? cfp[cid] : 0.f;
                const unsigned short* Xr = Xl + (size_t)cid*4096 + m16*256 + q16*8;
                f4v st  = {0.f,0.f,0.f,0.f};
                f4v st2 = {0.f,0.f,0.f,0.f};
                #pragma unroll
                for (int i = 0; i < 8; i += 2){
                    s8v A0 = *(const s8v*)(Xr + i*32);
                    s8v A1 = *(const s8v*)(Xr + (i+1)*32);
                    st  = __builtin_amdgcn_mfma_f32_16x16x32_bf16(A0, xa[i],   st,  0, 0, 0);
                    st2 = __builtin_amdgcn_mfma_f32_16x16x32_bf16(A1, xa[i+1], st2, 0, 0, 0);
                }
                h4 sv;
                #pragma unroll
                for (int r = 0; r < 4; ++r) sv[r] = (_Float16)((st[r] + st2[r])*cf);
                *(h4*)&ss[pb][lc][m16][q16*4] = sv;
            }
            __syncthreads();
            // PV: 4 chunk-pairs, K=32 f16 MFMA
            #pragma unroll
            for (int p = 0; p < 4; ++p){
                h8 sa = ldh8(&ss[pb][2*p + c01][m16][koff]);
                #pragma unroll
                for (int t = 0; t < 4; ++t){
                    const unsigned short* gp = Gl
                        + (size_t)(nb*8 + 2*p + c01)*4096
                        + (size_t)(wq + t*16 + m16)*16 + koff;
                    h8 gb = ldh8(gp);
                    hacc[t] = __builtin_amdgcn_mfma_f32_16x16x32_f16(sa, gb, hacc[t], 0, 0, 0);
                }
            }
            pb ^= 1;
        }
        if (l < 3){
            __syncthreads();   // all waves done reading xc
            #pragma unroll
            for (int t = 0; t < 4; ++t)
                #pragma unroll
                for (int r = 0; r < 4; ++r)
                    xc[4*q16 + r][wq + t*16 + m16] = f2b(silu_(hacc[t][r]));
            __syncthreads();
        }
    }

    // epilogue: post rmsnorm + shift + store
    float part[4] = {0,0,0,0};
    #pragma unroll
    for (int t = 0; t < 4; ++t)
        #pragma unroll
        for (int r = 0; r < 4; ++r) part[r] += hacc[t][r]*hacc[t][r];
    #pragma unroll
    for (int off = 1; off < 16; off <<= 1)
        #pragma unroll
        for (int r = 0; r < 4; ++r) part[r] += __shfl_xor(part[r], off, 64);
    if (m16 == 0)
        #pragma unroll
        for (int r = 0; r < 4; ++r) red[w][4*q16 + r] = part[r];
    __syncthreads();
    if (tid < 16){
        float s = red[0][tid] + red[1][tid] + red[2][tid] + red[3][tid];
        rs[tid] = rsqrtf(s*(1.f/256.f) + EPSf);
    }
    __syncthreads();
    #pragma unroll
    for (int t = 0; t < 4; ++t){
        int d = wq + t*16 + m16;
        float wp = wpost[d];
        #pragma unroll
        for (int r = 0; r < 4; ++r){
            int c = 4*q16 + r;
            int tp = nl*16 + c + 15;
            if (tp < 1024)
                out[((size_t)b*1024 + tp)*256 + d] = hacc[t][r]*rs[c]*wp;
        }
    }
    if (nl == 0){
        for (int idx = tid; idx < 15*256; idx += 256)
            out[(size_t)b*262144 + idx] = 0.f;
    }
}

extern "C" void kernel_launch(void* const* d_in, const int* in_sizes, int n_in,
                              void* d_out, int out_size, void* d_ws, size_t ws_size,
                              hipStream_t stream) {
    const float* seq     = (const float*)d_in[0];
    const float* w_store = (const float*)d_in[1];
    const float* w_retr  = (const float*)d_in[2];
    const float* w_post  = (const float*)d_in[3];
    const float* Wq      = (const float*)d_in[4];
    const float* Wkv     = (const float*)d_in[5];
    const float* w_adapt = (const float*)d_in[6];
    const float* w_mom   = (const float*)d_in[7];
    const float* w_decay = (const float*)d_in[8];
    const float* W0      = (const float*)d_in[9];
    const float* W1      = (const float*)d_in[10];
    const float* W2      = (const float*)d_in[11];
    const float* W3      = (const float*)d_in[12];

    float* momg  = (float*)d_ws;                  // 128
    float* decg  = momg + NCn;                    // 128
    float* coefb = decg + NCn;                    // 128*64 fp32
    unsigned short* snb   = (unsigned short*)(coefb + (size_t)NCn*64);
    unsigned short* rnb   = snb   + (size_t)NCn*4096;
    unsigned short* WTb   = rnb   + (size_t)NCn*4096;
    unsigned short* Wb    = WTb   + 4*(size_t)DDn;
    unsigned short* WqTb  = Wb    + 3*(size_t)DDn;
    unsigned short* WkvTb = WqTb  + (size_t)DDn;
    unsigned short* Xb    = WkvTb + 2*(size_t)DDn;      // bf16 [l][g][c][d], 4 MB
    unsigned short* GT    = Xb    + (size_t)4*NCn*4096; // f16  [l][g][d][c], 4 MB

    ktw   <<<dim3(8, 16, 9), 256, 0, stream>>>(Wq, Wkv, W0, W1, W2, W3,
                                               WTb, WqTb, WkvTb, Wb);
    knorm <<<dim3(2048),     256, 0, stream>>>(seq, w_store, w_retr, snb, rnb);
    kfb   <<<dim3(NCn),      512, 0, stream>>>(snb, WkvTb, WTb, Wb,
                                               w_adapt, w_mom, w_decay,
                                               momg, decg, Xb, GT);
    kcoef <<<dim3(2),         64, 0, stream>>>(momg, decg, coefb);
    kretr <<<dim3(NCn),      256, 0, stream>>>(rnb, WqTb, WTb, Xb, GT,
                                               coefb, w_post, (float*)d_out);
}

// Round 3
// 232.973 us; speedup vs baseline: 1.3631x; 1.3631x over previous
//
#include <hip/hip_runtime.h>
#include <hip/hip_bf16.h>

typedef __attribute__((ext_vector_type(8)))  short s8v;   // 8 bf16
typedef __attribute__((ext_vector_type(4)))  float f4v;   // 16x16 C/D
typedef _Float16 h4 __attribute__((ext_vector_type(4)));  // 4 f16
typedef _Float16 h8 __attribute__((ext_vector_type(8)));  // 8 f16
typedef __attribute__((ext_vector_type(4))) unsigned short u4v;

constexpr int NCn  = 128;
constexpr int DDn  = 65536;
constexpr int XP   = 264;             // padded LDS row (bf16 elems)
constexpr int SSP  = 24;              // padded score row (f16 elems, 48B)
constexpr float EPSf = 1.1920929e-07f;

__device__ __forceinline__ float sigm(float x){ return 1.0f/(1.0f + expf(-x)); }
__device__ __forceinline__ float silu_(float x){ return x * sigm(x); }
__device__ __forceinline__ float dsilu_(float x){ float s = sigm(x); return s*(1.0f + x*(1.0f - s)); }

__device__ __forceinline__ unsigned short f2b(float x){
    __hip_bfloat16 b = __float2bfloat16(x);
    unsigned short u; __builtin_memcpy(&u, &b, 2); return u;
}
__device__ __forceinline__ float b2f(unsigned short u){
    __hip_bfloat16 b; __builtin_memcpy(&b, &u, 2); return __bfloat162float(b);
}
__device__ __forceinline__ unsigned short f2hu(float x){
    _Float16 h = (_Float16)x;
    unsigned short u; __builtin_memcpy(&u, &h, 2); return u;
}
__device__ __forceinline__ h4 ldh4(const unsigned short* p){
    h4 r; __builtin_memcpy(&r, p, 8); return r;
}
__device__ __forceinline__ h8 ldh8(const void* p){
    h8 r; __builtin_memcpy(&r, p, 16); return r;
}

__device__ __forceinline__ float block_sum(float v, float* red){   // 256 thr
    #pragma unroll
    for (int off = 32; off; off >>= 1) v += __shfl_down(v, off, 64);
    if ((threadIdx.x & 63) == 0) red[threadIdx.x >> 6] = v;
    __syncthreads();
    float r = red[0] + red[1] + red[2] + red[3];
    __syncthreads();
    return r;
}
__device__ __forceinline__ float block_sum16(float v, float* red){ // 1024 thr
    #pragma unroll
    for (int off = 32; off; off >>= 1) v += __shfl_down(v, off, 64);
    if ((threadIdx.x & 63) == 0) red[threadIdx.x >> 6] = v;
    __syncthreads();
    float r = 0.f;
    #pragma unroll
    for (int i = 0; i < 16; ++i) r += red[i];
    __syncthreads();
    return r;
}

// ---- merged weight prep: z 0..5 tiled transpose fp32->bf16, z 6..8 cast-copy ----
__global__ __launch_bounds__(256) void ktw(const float* __restrict__ Wq,
        const float* __restrict__ Wkv, const float* __restrict__ W0,
        const float* __restrict__ W1, const float* __restrict__ W2,
        const float* __restrict__ W3, unsigned short* __restrict__ WTb,
        unsigned short* __restrict__ WqTb, unsigned short* __restrict__ WkvTb,
        unsigned short* __restrict__ Wb){
    int z = blockIdx.z;
    if (z >= 6){
        const float* S = (z==6)?W1:(z==7)?W2:W3;
        size_t idx = (((size_t)blockIdx.y*8 + blockIdx.x)*256 + threadIdx.x)*2;
        float2 v = *(const float2*)(S + idx);
        ushort2 u; u.x = f2b(v.x); u.y = f2b(v.y);
        *(ushort2*)(Wb + (size_t)(z-6)*DDn + idx) = u;
        return;
    }
    __shared__ float tl[32][33];
    if (z != 5 && blockIdx.y >= 8) return;
    const float* S; unsigned short* T; int C;
    if (z < 4){ S = (z==0)?W0:(z==1)?W1:(z==2)?W2:W3; T = WTb + (size_t)z*DDn; C = 256; }
    else if (z == 4){ S = Wq; T = WqTb; C = 256; }
    else { S = Wkv; T = WkvTb; C = 512; }
    int k0 = blockIdx.x*32, j0 = blockIdx.y*32;
    int tx = threadIdx.x & 31, ty = threadIdx.x >> 5;
    #pragma unroll
    for (int p = 0; p < 4; ++p)
        tl[ty + 8*p][tx] = S[(size_t)(k0 + ty + 8*p)*C + j0 + tx];
    __syncthreads();
    #pragma unroll
    for (int p = 0; p < 4; ++p)
        T[(size_t)(j0 + ty + 8*p)*256 + k0 + tx] = f2b(tl[tx][ty + 8*p]);
}

// ---- per-token norm, scatter sn + shifted rn ----
__global__ __launch_bounds__(256) void knorm(const float* __restrict__ seq,
        const float* __restrict__ wsn, const float* __restrict__ wrn,
        unsigned short* __restrict__ snb, unsigned short* __restrict__ rnb){
    __shared__ float red[4];
    int t = blockIdx.x, d = threadIdx.x;
    int b = t >> 10, tl = t & 1023, g = t >> 4, c = tl & 15;
    float x = seq[(size_t)t*256 + d];
    float ss = block_sum(x*x, red);
    float xr = x * rsqrtf(ss*(1.f/256.f) + EPSf);
    snb[(size_t)g*4096 + c*256 + d] = f2b(xr*wsn[d]);
    if (tl >= 15){
        int tl2 = tl - 15, g2 = b*64 + (tl2 >> 4), c2 = tl2 & 15;
        rnb[(size_t)g2*4096 + c2*256 + d] = f2b(xr*wrn[d]);
    }
    if (tl >= 1009)
        rnb[(size_t)g*4096 + c*256 + d] = 0;
}

// ---- fwd + bwd dgrads + fused gates, one block per group, 16 waves ----
// writes Xb bf16 [l][g][c][d], XT f16 [l][g][d][c], GT f16 [l][g][d][c]
__global__ __launch_bounds__(1024, 1) void kfb(const unsigned short* __restrict__ snb,
        const unsigned short* __restrict__ WkvTb, const unsigned short* __restrict__ WTb,
        const unsigned short* __restrict__ Wb,
        const float* __restrict__ wa, const float* __restrict__ wm,
        const float* __restrict__ wdk,
        float* __restrict__ momg, float* __restrict__ decg,
        unsigned short* __restrict__ Xb, unsigned short* __restrict__ XT,
        unsigned short* __restrict__ GT){
    __shared__ unsigned short xl[4][16][XP];
    __shared__ unsigned short Gs[16][XP];
    __shared__ float red16[16];
    int tid = threadIdx.x, w = tid >> 6, lane = tid & 63;
    int m16 = lane & 15, q16 = lane >> 4;
    int g = blockIdx.x;
    int n0 = w*16;

    float sc;
    {   // fused gates (all 1024 threads)
        int d2 = tid & 255, qt = tid >> 8;
        float a = 0.f;
        #pragma unroll
        for (int c = 0; c < 4; ++c)
            a += b2f(snb[(size_t)g*4096 + (qt*4 + c)*256 + d2]);
        float cm = a * (1.f/16.f);
        float da = block_sum16(cm*wa[d2],  red16);
        float dm = block_sum16(cm*wm[d2],  red16);
        float dc = block_sum16(cm*wdk[d2], red16);
        sc = -2.f * sigm(da) * (1.f/256.f);
        if (tid == 0){ momg[g] = sigm(dm); decg[g] = sigm(dc); }
    }

    s8v af[8];
    const unsigned short* arow = snb + (size_t)g*4096 + m16*256 + q16*8;
    #pragma unroll
    for (int i = 0; i < 8; ++i) af[i] = *(const s8v*)(arow + i*32);

    f4v vacc;
    {
        f4v ka = {0.f,0.f,0.f,0.f}, va = {0.f,0.f,0.f,0.f};
        const unsigned short* brK = WkvTb + (size_t)(n0 + m16)*256 + q16*8;
        const unsigned short* brV = WkvTb + (size_t)(256 + n0 + m16)*256 + q16*8;
        #pragma unroll
        for (int i = 0; i < 8; ++i){
            s8v bK = *(const s8v*)(brK + i*32);
            s8v bV = *(const s8v*)(brV + i*32);
            ka = __builtin_amdgcn_mfma_f32_16x16x32_bf16(af[i], bK, ka, 0, 0, 0);
            va = __builtin_amdgcn_mfma_f32_16x16x32_bf16(af[i], bV, va, 0, 0, 0);
        }
        vacc = va;
        #pragma unroll
        for (int r = 0; r < 4; ++r) xl[0][4*q16 + r][n0 + m16] = f2b(ka[r]);
    }

    f4v hreg[3];
    for (int l = 0; l < 3; ++l){
        __syncthreads();
        s8v xa[8];
        #pragma unroll
        for (int i = 0; i < 8; ++i)
            xa[i] = *(const s8v*)(&xl[l][m16][q16*8 + i*32]);
        const unsigned short* Wt = WTb + (size_t)l*DDn;
        f4v acc = {0.f,0.f,0.f,0.f};
        const unsigned short* br = Wt + (size_t)(n0 + m16)*256 + q16*8;
        #pragma unroll
        for (int i = 0; i < 8; ++i){
            s8v b = *(const s8v*)(br + i*32);
            acc = __builtin_amdgcn_mfma_f32_16x16x32_bf16(xa[i], b, acc, 0, 0, 0);
        }
        hreg[l] = acc;
        #pragma unroll
        for (int r = 0; r < 4; ++r)
            xl[l+1][4*q16 + r][n0 + m16] = f2b(silu_(acc[r]));
    }
    __syncthreads();

    {   // dump layer inputs Xb[l][g][c][d] bf16 (direct copy from xl)
        int c = tid >> 6, d4 = (tid & 63)*4;
        #pragma unroll
        for (int l = 0; l < 4; ++l)
            *(u4v*)(Xb + (((size_t)l*128 + g)*16 + c)*256 + d4) =
                *(const u4v*)(&xl[l][c][d4]);
    }
    {   // dump XT f16 [l][g][d][c]
        int d = tid & 255, qt = tid >> 8;
        #pragma unroll
        for (int l = 0; l < 4; ++l){
            h4 v;
            #pragma unroll
            for (int j = 0; j < 4; ++j)
                v[j] = (_Float16)b2f(xl[l][qt*4 + j][d]);
            *(h4*)(XT + (((size_t)l*128 + g)*256 + d)*16 + qt*4) = v;
        }
    }

    {   // layer 3 (pred) -> Gs
        s8v xa[8];
        #pragma unroll
        for (int i = 0; i < 8; ++i)
            xa[i] = *(const s8v*)(&xl[3][m16][q16*8 + i*32]);
        const unsigned short* Wt = WTb + (size_t)3*DDn;
        f4v acc = {0.f,0.f,0.f,0.f};
        const unsigned short* br = Wt + (size_t)(n0 + m16)*256 + q16*8;
        #pragma unroll
        for (int i = 0; i < 8; ++i){
            s8v b = *(const s8v*)(br + i*32);
            acc = __builtin_amdgcn_mfma_f32_16x16x32_bf16(xa[i], b, acc, 0, 0, 0);
        }
        #pragma unroll
        for (int r = 0; r < 4; ++r)
            Gs[4*q16 + r][n0 + m16] = f2b(sc * (acc[r] - vacc[r]));
    }
    __syncthreads();
    {   // write f16 GT[3][g][d][c]
        int d = tid & 255, qt = tid >> 8;
        h4 v;
        #pragma unroll
        for (int j = 0; j < 4; ++j)
            v[j] = (_Float16)b2f(Gs[qt*4 + j][d]);
        *(h4*)(GT + (((size_t)3*128 + g)*256 + d)*16 + qt*4) = v;
    }

    for (int l = 3; l >= 1; --l){
        s8v gfa[8];
        #pragma unroll
        for (int i = 0; i < 8; ++i)
            gfa[i] = *(const s8v*)(&Gs[m16][q16*8 + i*32]);
        const unsigned short* Wr = Wb + (size_t)(l-1)*DDn;
        f4v acc = {0.f,0.f,0.f,0.f};
        const unsigned short* br = Wr + (size_t)(n0 + m16)*256 + q16*8;
        #pragma unroll
        for (int i = 0; i < 8; ++i){
            s8v b = *(const s8v*)(br + i*32);
            acc = __builtin_amdgcn_mfma_f32_16x16x32_bf16(gfa[i], b, acc, 0, 0, 0);
        }
        f4v gn;
        #pragma unroll
        for (int r = 0; r < 4; ++r)
            gn[r] = acc[r] * dsilu_(hreg[l-1][r]);
        __syncthreads();
        #pragma unroll
        for (int r = 0; r < 4; ++r)
            Gs[4*q16 + r][n0 + m16] = f2b(gn[r]);
        __syncthreads();
        {
            int d = tid & 255, qt = tid >> 8;
            h4 v;
            #pragma unroll
            for (int j = 0; j < 4; ++j)
                v[j] = (_Float16)b2f(Gs[qt*4 + j][d]);
            *(h4*)(GT + (((size_t)(l-1)*128 + g)*256 + d)*16 + qt*4) = v;
        }
    }
}

// ---- coefficients: cf(g,n), mp(g,n), and per-g segment scalars A_g,B_g,PImo_g ----
__global__ __launch_bounds__(64) void kcoef(const float* __restrict__ momg,
        const float* __restrict__ decg, float* __restrict__ coefb,
        float* __restrict__ mpb, float* __restrict__ apg,
        float* __restrict__ bpg, float* __restrict__ mpg){
    int b = blockIdx.x, n = threadIdx.x;
    float M = 0.f, cf = 0.f;
    for (int gg = 0; gg < 64; ++gg){
        float mo = momg[b*64 + gg], de = 1.f - decg[b*64 + gg];
        if (gg == n){ M = 1.f; cf = 1.f; }
        else if (gg > n){ M *= mo; cf = de*cf + M; }
        coefb[((size_t)b*64 + gg)*64 + n] = cf;
        mpb  [((size_t)b*64 + gg)*64 + n] = M;
    }
    // per-g (thread n = g): A = prod de over segment up to g; B (Mcp coupling); pm = prod mo
    int ss0 = n & ~7;
    float a = 1.f, B = 0.f, pm = 1.f;
    for (int j = ss0; j <= n; ++j){
        float mo = momg[b*64 + j], de = 1.f - decg[b*64 + j];
        pm *= mo; B = de*B + pm; a *= de;
    }
    apg[b*64 + n] = a; bpg[b*64 + n] = B; mpg[b*64 + n] = pm;
}

// ---- per-segment partial sums Pu_s = sum cf(e_s,n) S_n, Pm_s = sum mp(e_s,n) S_n ----
// grid (4 rowtiles, 7 segs, 8 bl=b*4+l), 256 thr; outputs f32 [bl][s][dout][din]
__global__ __launch_bounds__(256, 1) void kpart(const unsigned short* __restrict__ XT,
        const unsigned short* __restrict__ GT, const float* __restrict__ coefb,
        const float* __restrict__ mpb, float* __restrict__ pub,
        float* __restrict__ pmb){
    int lane = threadIdx.x & 63, w = threadIdx.x >> 6;
    int m16 = lane & 15, q16 = lane >> 4;
    int rt = blockIdx.x, s = blockIdx.y, bl = blockIdx.z;
    int b = bl >> 2, l = bl & 3;
    int e = s*8 + 7;
    const float* cfr = coefb + ((size_t)b*64 + e)*64;
    const float* mpr = mpb   + ((size_t)b*64 + e)*64;
    int d2 = rt*64 + w*16 + m16;
    h4 au[8], am[8];
    #pragma unroll
    for (int n = 0; n < 8; ++n){
        int cid = s*8 + n;
        h4 a = ldh4(GT + (((size_t)l*128 + b*64 + cid)*256 + d2)*16 + q16*4);
        _Float16 cfh = (_Float16)cfr[cid];
        _Float16 mph = (_Float16)mpr[cid];
        au[n] = a*cfh; am[n] = a*mph;
    }
    for (int ct = 0; ct < 16; ++ct){
        int d1 = ct*16 + m16;
        f4v acu = {0.f,0.f,0.f,0.f}, acm = {0.f,0.f,0.f,0.f};
        #pragma unroll
        for (int n = 0; n < 8; ++n){
            int cid = s*8 + n;
            h4 xb = ldh4(XT + (((size_t)l*128 + b*64 + cid)*256 + d1)*16 + q16*4);
            acu = __builtin_amdgcn_mfma_f32_16x16x16f16(au[n], xb, acu, 0, 0, 0);
            acm = __builtin_amdgcn_mfma_f32_16x16x16f16(am[n], xb, acm, 0, 0, 0);
        }
        size_t ob = (((size_t)bl*7 + s)*256 + (size_t)(rt*64 + w*16))*256 + d1;
        #pragma unroll
        for (int r = 0; r < 4; ++r){
            pub[ob + (size_t)(4*q16 + r)*256] = acu[r];
            pmb[ob + (size_t)(4*q16 + r)*256] = acm[r];
        }
    }
}

// ---- elementwise 7-step scan: checkpoints Ucp/Mcp (bf16) ----
// grid (8 bl, 16), 256 thr, 16 elems/thread
__global__ __launch_bounds__(256) void kcmb(const float* __restrict__ pub,
        const float* __restrict__ pmb, const float* __restrict__ apg,
        const float* __restrict__ bpg, const float* __restrict__ mpg,
        unsigned short* __restrict__ ucpb, unsigned short* __restrict__ mcpb){
    int bl = blockIdx.x, b = bl >> 2;
    size_t base = (size_t)blockIdx.y*4096 + (size_t)threadIdx.x*16;
    float u[16], m[16];
    #pragma unroll
    for (int i = 0; i < 16; ++i){ u[i] = 0.f; m[i] = 0.f; }
    for (int s = 0; s < 7; ++s){
        int idx = b*64 + s*8 + 7;
        float av = apg[idx], bv = bpg[idx], mv = mpg[idx];
        size_t off = ((size_t)bl*7 + s)*65536 + base;
        #pragma unroll
        for (int v = 0; v < 4; ++v){
            float4 fu = *(const float4*)(pub + off + v*4);
            float4 fm = *(const float4*)(pmb + off + v*4);
            const float* fup = (const float*)&fu;
            const float* fmp = (const float*)&fm;
            u4v su, sm;
            #pragma unroll
            for (int j = 0; j < 4; ++j){
                int i = v*4 + j;
                float un = av*u[i] + bv*m[i] + fup[j];
                float mn = mv*m[i] + fmp[j];
                u[i] = un; m[i] = mn;
                su[j] = f2b(un); sm[j] = f2b(mn);
            }
            *(u4v*)(ucpb + off + v*4) = su;
            *(u4v*)(mcpb + off + v*4) = sm;
        }
    }
}

// ---- retrieval: q-proj + 4 layers {x@(W + A*Ucp + B*Mcp) + local <=8-chunk scan} ----
// one block per group g; 16 waves, wave w owns cols [w*16, w*16+16)
__global__ __launch_bounds__(1024, 1) void kretr(const unsigned short* __restrict__ rnb,
        const unsigned short* __restrict__ WqTb, const unsigned short* __restrict__ WTb,
        const unsigned short* __restrict__ ucpb, const unsigned short* __restrict__ mcpb,
        const unsigned short* __restrict__ Xb, const unsigned short* __restrict__ GT,
        const float* __restrict__ coefb, const float* __restrict__ apg,
        const float* __restrict__ bpg, const float* __restrict__ wpost,
        float* __restrict__ out){
    __shared__ unsigned short xc[16][XP];
    __shared__ _Float16 ss[8][16][SSP];
    __shared__ float red[16][16];
    __shared__ float rs[16];
    int tid = threadIdx.x, w = tid >> 6, lane = tid & 63;
    int m16 = lane & 15, q16 = lane >> 4;
    int g = blockIdx.x, b = g >> 6, nl = g & 63;
    int seg = nl >> 3, cnt = (nl & 7) + 1, sbase = seg*8;
    int n0 = w*16;
    int c01 = q16 >> 1, koff = (q16 & 1)*8;

    {   // q-projection
        s8v a[8];
        const unsigned short* ar = rnb + (size_t)g*4096 + m16*256 + q16*8;
        #pragma unroll
        for (int i = 0; i < 8; ++i) a[i] = *(const s8v*)(ar + i*32);
        f4v acc = {0.f,0.f,0.f,0.f};
        const unsigned short* br = WqTb + (size_t)(n0 + m16)*256 + q16*8;
        #pragma unroll
        for (int i = 0; i < 8; ++i){
            s8v bb = *(const s8v*)(br + i*32);
            acc = __builtin_amdgcn_mfma_f32_16x16x32_bf16(a[i], bb, acc, 0, 0, 0);
        }
        #pragma unroll
        for (int r = 0; r < 4; ++r) xc[4*q16 + r][n0 + m16] = f2b(acc[r]);
    }
    __syncthreads();

    float ua = apg[g], ub = bpg[g];
    const float* cfp = coefb + (size_t)g*64;
    f4v hacc;
    for (int l = 0; l < 4; ++l){
        s8v xa[8];
        #pragma unroll
        for (int i = 0; i < 8; ++i)
            xa[i] = *(const s8v*)(&xc[m16][q16*8 + i*32]);
        // dense: x @ (W + A*Ucp + B*Mcp)
        {
            const unsigned short* br = WTb + (size_t)l*DDn + (size_t)(n0 + m16)*256 + q16*8;
            f4v aW = {0.f,0.f,0.f,0.f};
            if (seg){
                size_t cko = ((size_t)(b*4 + l)*7 + (seg-1))*65536 + (size_t)(n0 + m16)*256 + q16*8;
                const unsigned short* bu = ucpb + cko;
                const unsigned short* bm = mcpb + cko;
                f4v aU = {0.f,0.f,0.f,0.f}, aM = {0.f,0.f,0.f,0.f};
                #pragma unroll
                for (int i = 0; i < 8; ++i){
                    s8v w0 = *(const s8v*)(br + i*32);
                    s8v u0 = *(const s8v*)(bu + i*32);
                    s8v m0 = *(const s8v*)(bm + i*32);
                    aW = __builtin_amdgcn_mfma_f32_16x16x32_bf16(xa[i], w0, aW, 0, 0, 0);
                    aU = __builtin_amdgcn_mfma_f32_16x16x32_bf16(xa[i], u0, aU, 0, 0, 0);
                    aM = __builtin_amdgcn_mfma_f32_16x16x32_bf16(xa[i], m0, aM, 0, 0, 0);
                }
                #pragma unroll
                for (int r = 0; r < 4; ++r) hacc[r] = aW[r] + ua*aU[r] + ub*aM[r];
            } else {
                #pragma unroll
                for (int i = 0; i < 8; ++i){
                    s8v w0 = *(const s8v*)(br + i*32);
                    aW = __builtin_amdgcn_mfma_f32_16x16x32_bf16(xa[i], w0, aW, 0, 0, 0);
                }
                hacc = aW;
            }
        }
        // local scores: waves 0..7, chunk sbase+w (zero-padded past cnt)
        if (w < 8){
            h4 sv = {(_Float16)0.f,(_Float16)0.f,(_Float16)0.f,(_Float16)0.f};
            if (w < cnt){
                int cid = sbase + w;
                float cf = cfp[cid];
                const unsigned short* Xr = Xb + ((size_t)l*128 + b*64 + cid)*4096
                                         + m16*256 + q16*8;
                f4v st  = {0.f,0.f,0.f,0.f};
                f4v st2 = {0.f,0.f,0.f,0.f};
                #pragma unroll
                for (int i = 0; i < 8; i += 2){
                    s8v A0 = *(const s8v*)(Xr + i*32);
                    s8v A1 = *(const s8v*)(Xr + (i+1)*32);
                    st  = __builtin_amdgcn_mfma_f32_16x16x32_bf16(A0, xa[i],   st,  0, 0, 0);
                    st2 = __builtin_amdgcn_mfma_f32_16x16x32_bf16(A1, xa[i+1], st2, 0, 0, 0);
                }
                #pragma unroll
                for (int r = 0; r < 4; ++r) sv[r] = (_Float16)((st[r] + st2[r])*cf);
            }
            *(h4*)&ss[w][m16][q16*4] = sv;
        }
        __syncthreads();
        // PV: chunk pairs, K=32 f16
        int npair = (cnt + 1) >> 1;
        for (int p = 0; p < npair; ++p){
            h8 sa = ldh8(&ss[2*p + c01][m16][koff]);
            const unsigned short* gp = GT + ((size_t)l*128 + b*64 + sbase + 2*p + c01)*4096
                                     + (size_t)(n0 + m16)*16 + koff;
            h8 gb = ldh8(gp);
            hacc = __builtin_amdgcn_mfma_f32_16x16x32_f16(sa, gb, hacc, 0, 0, 0);
        }
        if (l < 3){
            __syncthreads();
            #pragma unroll
            for (int r = 0; r < 4; ++r)
                xc[4*q16 + r][n0 + m16] = f2b(silu_(hacc[r]));
            __syncthreads();
        }
    }

    // epilogue: post rmsnorm + shift + store
    float part[4];
    #pragma unroll
    for (int r = 0; r < 4; ++r) part[r] = hacc[r]*hacc[r];
    #pragma unroll
    for (int off = 1; off < 16; off <<= 1)
        #pragma unroll
        for (int r = 0; r < 4; ++r) part[r] += __shfl_xor(part[r], off, 64);
    if (m16 == 0)
        #pragma unroll
        for (int r = 0; r < 4; ++r) red[w][4*q16 + r] = part[r];
    __syncthreads();
    if (tid < 16){
        float s = 0.f;
        #pragma unroll
        for (int i = 0; i < 16; ++i) s += red[i][tid];
        rs[tid] = rsqrtf(s*(1.f/256.f) + EPSf);
    }
    __syncthreads();
    {
        int d = n0 + m16;
        float wp = wpost[d];
        #pragma unroll
        for (int r = 0; r < 4; ++r){
            int c = 4*q16 + r;
            int tp = nl*16 + c + 15;
            if (tp < 1024)
                out[((size_t)b*1024 + tp)*256 + d] = hacc[r]*rs[c]*wp;
        }
    }
    if (nl == 0){
        for (int idx = tid; idx < 15*256; idx += 1024)
            out[(size_t)b*262144 + idx] = 0.f;
    }
}

extern "C" void kernel_launch(void* const* d_in, const int* in_sizes, int n_in,
                              void* d_out, int out_size, void* d_ws, size_t ws_size,
                              hipStream_t stream) {
    const float* seq     = (const float*)d_in[0];
    const float* w_store = (const float*)d_in[1];
    const float* w_retr  = (const float*)d_in[2];
    const float* w_post  = (const float*)d_in[3];
    const float* Wq      = (const float*)d_in[4];
    const float* Wkv     = (const float*)d_in[5];
    const float* w_adapt = (const float*)d_in[6];
    const float* w_mom   = (const float*)d_in[7];
    const float* w_decay = (const float*)d_in[8];
    const float* W0      = (const float*)d_in[9];
    const float* W1      = (const float*)d_in[10];
    const float* W2      = (const float*)d_in[11];
    const float* W3      = (const float*)d_in[12];

    float* momg  = (float*)d_ws;                       // 128
    float* decg  = momg + NCn;                         // 128
    float* coefb = decg + NCn;                         // 8192
    float* mpb   = coefb + (size_t)NCn*64;             // 8192
    float* apg   = mpb + (size_t)NCn*64;               // 128
    float* bpg   = apg + NCn;                          // 128
    float* mpg   = bpg + NCn;                          // 128
    float* pub   = mpg + NCn + 32;                     // 8*7*65536 f32
    float* pmb   = pub + (size_t)8*7*65536;            // 8*7*65536 f32
    unsigned short* snb   = (unsigned short*)(pmb + (size_t)8*7*65536);
    unsigned short* rnb   = snb   + (size_t)NCn*4096;
    unsigned short* WTb   = rnb   + (size_t)NCn*4096;
    unsigned short* Wb    = WTb   + 4*(size_t)DDn;
    unsigned short* WqTb  = Wb    + 3*(size_t)DDn;
    unsigned short* WkvTb = WqTb  + (size_t)DDn;
    unsigned short* Xb    = WkvTb + 2*(size_t)DDn;       // bf16 [l][g][c][d], 4 MB
    unsigned short* XT    = Xb    + (size_t)4*NCn*4096;  // f16  [l][g][d][c], 4 MB
    unsigned short* GT    = XT    + (size_t)4*NCn*4096;  // f16  [l][g][d][c], 4 MB
    unsigned short* ucpb  = GT    + (size_t)4*NCn*4096;  // bf16 [bl][7][256][256]
    unsigned short* mcpb  = ucpb  + (size_t)8*7*65536;   // bf16 [bl][7][256][256]

    ktw   <<<dim3(8, 16, 9), 256,  0, stream>>>(Wq, Wkv, W0, W1, W2, W3,
                                                WTb, WqTb, WkvTb, Wb);
    knorm <<<dim3(2048),     256,  0, stream>>>(seq, w_store, w_retr, snb, rnb);
    kfb   <<<dim3(NCn),      1024, 0, stream>>>(snb, WkvTb, WTb, Wb,
                                                w_adapt, w_mom, w_decay,
                                                momg, decg, Xb, XT, GT);
    kcoef <<<dim3(2),        64,   0, stream>>>(momg, decg, coefb, mpb, apg, bpg, mpg);
    kpart <<<dim3(4, 7, 8),  256,  0, stream>>>(XT, GT, coefb, mpb, pub, pmb);
    kcmb  <<<dim3(8, 16),    256,  0, stream>>>(pub, pmb, apg, bpg, mpg, ucpb, mcpb);
    kretr <<<dim3(NCn),      1024, 0, stream>>>(rnb, WqTb, WTb, ucpb, mcpb, Xb, GT,
                                                coefb, apg, bpg, w_post, (float*)d_out);
}